// Round 9
// baseline (27.705 us; speedup 1.0000x reference)
//
#include <hip/hip_runtime.h>

#define Wd 512
#define Hd 512
#define NIMG 48                      // 16 batch * 3 channels
#define RB 16                        // output rows per tile
#define LR (RB + 2)                  // staged rows incl. vertical halo
#define NBLK (NIMG * (Hd / RB))      // 48*32 = 1536 blocks, one tile each
constexpr float INV_N = 1.0f / (float)((long long)NIMG * Hd * Wd);

// async global->LDS, 16 B per lane: HW writes lds_base + lane*16.
__device__ __forceinline__ void gload_lds16(const float* g, float* l) {
    __builtin_amdgcn_global_load_lds(
        (const __attribute__((address_space(1))) void*)g,
        (__attribute__((address_space(3))) void*)l, 16, 0, 0);
}

// Scharr on a 3x10 window; pixel j (0..7) uses cols j..j+2 of rows r0,r1,r2.
__device__ __forceinline__ float scharr_pix(const float r0[10], const float r1[10],
                                            const float r2[10], int j) {
    float tl = r0[j], tm = r0[j + 1], tr = r0[j + 2];
    float ml = r1[j],                  mr = r1[j + 2];
    float bl = r2[j], bm = r2[j + 1], br = r2[j + 2];
    float gx = 3.f * (tr - tl) + 10.f * (mr - ml) + 3.f * (br - bl);
    float gy = 3.f * (bl - tl) + 10.f * (bm - tm) + 3.f * (br - tr);
    return fabsf(gx) + fabsf(gy);
}

// Read cols [c0-1 .. c0+8] of one staged LDS row; halo via neighbor-lane shfl
// (wave spans the full 512-col row, lane edges == image edges -> zero).
__device__ __forceinline__ void lds_row(const float* __restrict__ row, int lane,
                                        float r[10]) {
    float4 b0 = *reinterpret_cast<const float4*>(row + lane * 8);
    float4 b1 = *reinterpret_cast<const float4*>(row + lane * 8 + 4);
    r[1] = b0.x; r[2] = b0.y; r[3] = b0.z; r[4] = b0.w;
    r[5] = b1.x; r[6] = b1.y; r[7] = b1.z; r[8] = b1.w;
    float lv = __shfl_up(b1.w, 1, 64);     // lane-1's col c0-1
    float rv = __shfl_down(b0.x, 1, 64);   // lane+1's col c0+8
    r[0] = (lane > 0)  ? lv : 0.f;
    r[9] = (lane < 63) ? rv : 0.f;
}

__global__ void __launch_bounds__(512, 4)
scharr_loss_kernel(const float* __restrict__ x, const float* __restrict__ gt,
                   float* __restrict__ partials) {
    __shared__ float lb[2][LR][Wd];      // 72 KB -> 2 blocks/CU, 16 waves/CU
    __shared__ float ws[8];

    int wid  = threadIdx.x >> 6;         // 0..7
    int lane = threadIdx.x & 63;

    // Bijective XCD swizzle (NBLK % 8 == 0): consecutive tiles of one image
    // land on the same XCD -> block-boundary halo rows are L2 hits.
    int b    = blockIdx.x;
    int swz  = (b & 7) * (NBLK / 8) + (b >> 3);
    int img  = swz >> 5;                 // 32 tiles per image
    int trow = swz & 31;
    int h0   = trow * RB;

    const float* __restrict__ xb = x  + (size_t)img * Hd * Wd;
    const float* __restrict__ gb = gt + (size_t)img * Hd * Wd;

    // --- stage phase A: lb rows 0..9 (40 chunks of 1 KB, 5 per wave) ---
    #pragma unroll
    for (int t = 0; t < 5; ++t) {
        int c    = wid + t * 8;          // wave-uniform
        int im   = (c >= 20) ? 1 : 0;
        int cc   = c - im * 20;
        int row  = cc >> 1;
        int half = cc & 1;
        int gh   = h0 - 1 + row;
        const float* __restrict__ sb = im ? gb : xb;
        float* dst = &lb[im][row][half * 256];
        if ((unsigned)gh < (unsigned)Hd) {
            gload_lds16(sb + (size_t)gh * Wd + half * 256 + lane * 4, dst);
        } else {
            *reinterpret_cast<float4*>(dst + lane * 4) =
                make_float4(0.f, 0.f, 0.f, 0.f);
        }
    }
    // --- stage phase B: lb rows 10..17 (32 chunks, 4 per wave) ---
    #pragma unroll
    for (int t = 0; t < 4; ++t) {
        int c    = wid + t * 8;
        int im   = (c >= 16) ? 1 : 0;
        int cc   = c - im * 16;
        int row  = 10 + (cc >> 1);
        int half = cc & 1;
        int gh   = h0 - 1 + row;
        const float* __restrict__ sb = im ? gb : xb;
        float* dst = &lb[im][row][half * 256];
        if ((unsigned)gh < (unsigned)Hd) {
            gload_lds16(sb + (size_t)gh * Wd + half * 256 + lane * 4, dst);
        } else {
            *reinterpret_cast<float4*>(dst + lane * 4) =
                make_float4(0.f, 0.f, 0.f, 0.f);
        }
    }

    // Barrier 1: phase-A loads complete, phase-B still in flight (counted
    // vmcnt, in-order retirement: per-wave B-issues = 4 interior/top, 2 on
    // bottom tiles where waves 6,7 zero-fill row 17). lgkmcnt(0) covers
    // zero-fill ds_writes.
    if (trow == 31) {
        asm volatile("s_waitcnt vmcnt(2) lgkmcnt(0)" ::: "memory");
    } else {
        asm volatile("s_waitcnt vmcnt(4) lgkmcnt(0)" ::: "memory");
    }
    __builtin_amdgcn_sched_barrier(0);
    __builtin_amdgcn_s_barrier();
    __builtin_amdgcn_sched_barrier(0);

    float sum = 0.f;
    auto compute2 = [&](int lr) {        // 2 output rows from lb rows lr..lr+3
        float rx[3][10], rg[3][10];
        lds_row(&lb[0][lr][0],     lane, rx[0]);
        lds_row(&lb[0][lr + 1][0], lane, rx[1]);
        lds_row(&lb[1][lr][0],     lane, rg[0]);
        lds_row(&lb[1][lr + 1][0], lane, rg[1]);
        #pragma unroll
        for (int i = 0; i < 2; ++i) {
            const int c0 = i % 3, c1 = (i + 1) % 3, c2 = (i + 2) % 3;
            lds_row(&lb[0][lr + i + 2][0], lane, rx[c2]);
            lds_row(&lb[1][lr + i + 2][0], lane, rg[c2]);
            #pragma unroll
            for (int j = 0; j < 8; ++j) {
                float a = scharr_pix(rx[c0], rx[c1], rx[c2], j);
                float g = scharr_pix(rg[c0], rg[c1], rg[c2], j);
                sum += fabsf(a - g);
            }
        }
    };

    // phase 1: waves 0..3 compute output rows 0..7 (lb rows <= 9, all in A)
    if (wid < 4) compute2(wid * 2);

    __syncthreads();                     // vmcnt(0): phase-B loads landed

    // phase 2: waves 4..7 compute output rows 8..15 (lb rows 8..17)
    if (wid >= 4) compute2(8 + (wid - 4) * 2);

    // wave reduce -> cross-wave LDS -> one plain store per block
    #pragma unroll
    for (int off = 32; off > 0; off >>= 1)
        sum += __shfl_down(sum, off, 64);
    if (lane == 0) ws[wid] = sum;
    __syncthreads();
    if (threadIdx.x == 0) {
        float s = ws[0] + ws[1] + ws[2] + ws[3]
                + ws[4] + ws[5] + ws[6] + ws[7];
        partials[blockIdx.x] = s;
    }
}

__global__ void __launch_bounds__(256)
reduce_partials_kernel(const float* __restrict__ partials, float* __restrict__ out) {
    float s = 0.f;
    #pragma unroll
    for (int k = 0; k < NBLK / 256; ++k)          // 6 iterations
        s += partials[k * 256 + threadIdx.x];
    #pragma unroll
    for (int off = 32; off > 0; off >>= 1)
        s += __shfl_down(s, off, 64);
    __shared__ float ws[4];
    int lane = threadIdx.x & 63;
    int wid  = threadIdx.x >> 6;
    if (lane == 0) ws[wid] = s;
    __syncthreads();
    if (threadIdx.x == 0)
        out[0] = (ws[0] + ws[1] + ws[2] + ws[3]) * INV_N;
}

extern "C" void kernel_launch(void* const* d_in, const int* in_sizes, int n_in,
                              void* d_out, int out_size, void* d_ws, size_t ws_size,
                              hipStream_t stream) {
    const float* x  = (const float*)d_in[0];
    const float* gt = (const float*)d_in[1];
    float* out      = (float*)d_out;
    float* partials = (float*)d_ws;      // NBLK floats = 6 KB

    scharr_loss_kernel<<<NBLK, 512, 0, stream>>>(x, gt, partials);
    reduce_partials_kernel<<<1, 256, 0, stream>>>(partials, out);
}